// Round 6
// baseline (4520.631 us; speedup 1.0000x reference)
//
#include <hip/hip_runtime.h>

// Problem dims (fixed by setup_inputs): T=256, B=64, I=512, H=2048
#define T_DIM 256
#define B_DIM 64
#define I_DIM 512
#define H_DIM 2048
#define BH (B_DIM * H_DIM)      // 131072 floats per timestep slice
#define NBLK 256                // persistent grid: 1 block per CU
#define KG 8                    // k-groups (k-range 256)
#define NG 32                   // n-groups (n-range 64)
#define KR 256                  // k_range per block

typedef __attribute__((ext_vector_type(8))) short bf16x8;
typedef __attribute__((ext_vector_type(4))) float f32x4;

// ---------------------------------------------------------------------
// Agent-scope ops: write-through to MALL (stores), MALL-serviced (loads).
// Validated R4/R5. Used ONLY where addresses are rewritten+reread across
// XCDs (partials, h writes). h READS are normal loads + per-step acquire
// fence (L2 inv) so the 32 same-k-slice blocks share one L2 fill per XCD.
// ---------------------------------------------------------------------
__device__ __forceinline__ float2 aload8(const float* p) {
  union { unsigned long long u; float2 f; } c;
  c.u = __hip_atomic_load((const unsigned long long*)p, __ATOMIC_RELAXED,
                          __HIP_MEMORY_SCOPE_AGENT);
  return c.f;
}
__device__ __forceinline__ void astore8(float* p, float a, float b) {
  union { unsigned long long u; float2 f; } c; c.f = make_float2(a, b);
  __hip_atomic_store((unsigned long long*)p, c.u, __ATOMIC_RELAXED,
                     __HIP_MEMORY_SCOPE_AGENT);
}
__device__ __forceinline__ void astore4(float* p, float a) {
  union { unsigned u; float f; } c; c.f = a;
  __hip_atomic_store((unsigned*)p, c.u, __ATOMIC_RELAXED,
                     __HIP_MEMORY_SCOPE_AGENT);
}

// bf16 split: hi = RNE(x), lo = RNE(x - hi).
__device__ __forceinline__ unsigned bf16_rne(float x) {
  union { float f; unsigned u; } c; c.f = x;
  return (c.u + 0x7FFFu + ((c.u >> 16) & 1u)) >> 16;
}
__device__ __forceinline__ float bf16_to_f(unsigned b) {
  union { float f; unsigned u; } c; c.u = b << 16; return c.f;
}
__device__ __forceinline__ void cvt_pair(float x0, float x1,
                                         unsigned& hi, unsigned& lo) {
  unsigned h0 = bf16_rne(x0), h1 = bf16_rne(x1);
  float r0 = x0 - bf16_to_f(h0), r1 = x1 - bf16_to_f(h1);
  unsigned l0 = bf16_rne(r0), l1 = bf16_rne(r1);
  hi = h0 | (h1 << 16);
  lo = l0 | (l1 << 16);
}
// 8 consecutive floats -> one 16B hi frag + one 16B lo frag
__device__ __forceinline__ void cvt8(const float* s, uint4& hi, uint4& lo) {
  float4 a = *(const float4*)s;
  float4 b = *(const float4*)(s + 4);
  cvt_pair(a.x, a.y, hi.x, lo.x);
  cvt_pair(a.z, a.w, hi.y, lo.y);
  cvt_pair(b.x, b.y, hi.z, lo.z);
  cvt_pair(b.z, b.w, hi.w, lo.w);
}

// =====================================================================
// Kernel A: xin = x @ W_ih^T + b_ih + b_hh  (rows m<64 fold t=0:
// out[0] = 0.01*relu(xin[0])).  Unchanged (fp32 VALU, ~200us).
// =====================================================================
__global__ __launch_bounds__(256) void xin_gemm(
    const float* __restrict__ x, const float* __restrict__ Wih,
    const float* __restrict__ bih, const float* __restrict__ bhh,
    float* __restrict__ out)
{
  __shared__ __align__(16) float As[16][132];
  __shared__ __align__(16) float Bs[16][132];
  const int tid = threadIdx.x;
  const int nb = blockIdx.x & 15, mb = blockIdx.x >> 4;
  const int m0 = mb * 128, n0 = nb * 128;
  const int tx = tid & 15, ty = tid >> 4;

  float acc[8][8];
  #pragma unroll
  for (int i = 0; i < 8; ++i)
    #pragma unroll
    for (int j = 0; j < 8; ++j) acc[i][j] = 0.f;

  for (int k0 = 0; k0 < I_DIM; k0 += 16) {
    __syncthreads();
    {
      const int r = tid >> 1;
      #pragma unroll
      for (int c = 0; c < 2; ++c) {
        const int kq = (tid & 1) * 4 + c * 8;
        float4 va = *(const float4*)&x[(size_t)(m0 + r) * I_DIM + k0 + kq];
        As[kq + 0][r] = va.x; As[kq + 1][r] = va.y;
        As[kq + 2][r] = va.z; As[kq + 3][r] = va.w;
        float4 vb = *(const float4*)&Wih[(size_t)(n0 + r) * I_DIM + k0 + kq];
        Bs[kq + 0][r] = vb.x; Bs[kq + 1][r] = vb.y;
        Bs[kq + 2][r] = vb.z; Bs[kq + 3][r] = vb.w;
      }
    }
    __syncthreads();
    #pragma unroll 4
    for (int k = 0; k < 16; ++k) {
      float a[8], b[8];
      *(float4*)&a[0] = *(const float4*)&As[k][ty * 8];
      *(float4*)&a[4] = *(const float4*)&As[k][ty * 8 + 4];
      *(float4*)&b[0] = *(const float4*)&Bs[k][tx * 4];
      *(float4*)&b[4] = *(const float4*)&Bs[k][64 + tx * 4];
      #pragma unroll
      for (int i = 0; i < 8; ++i)
        #pragma unroll
        for (int j = 0; j < 8; ++j) acc[i][j] += a[i] * b[j];
    }
  }

  float bb[8];
  #pragma unroll
  for (int j = 0; j < 4; ++j) {
    bb[j]     = bih[n0 + tx * 4 + j]      + bhh[n0 + tx * 4 + j];
    bb[4 + j] = bih[n0 + 64 + tx * 4 + j] + bhh[n0 + 64 + tx * 4 + j];
  }
  #pragma unroll
  for (int i = 0; i < 8; ++i) {
    const int m = m0 + ty * 8 + i;
    float v[8];
    #pragma unroll
    for (int j = 0; j < 8; ++j) v[j] = acc[i][j] + bb[j];
    if (m < B_DIM) {
      #pragma unroll
      for (int j = 0; j < 8; ++j) v[j] = 0.01f * fmaxf(v[j], 0.f);
    }
    *(float4*)&out[(size_t)m * H_DIM + n0 + tx * 4] =
        make_float4(v[0], v[1], v[2], v[3]);
    *(float4*)&out[(size_t)m * H_DIM + n0 + 64 + tx * 4] =
        make_float4(v[4], v[5], v[6], v[7]);
  }
}

// ---------------------------------------------------------------------
// Fence-free grid barrier (validated R4/R5).
// ---------------------------------------------------------------------
__device__ __forceinline__ void gbar(unsigned* slots, unsigned m, int bid) {
  asm volatile("s_waitcnt vmcnt(0) lgkmcnt(0)" ::: "memory");
  __syncthreads();
  if (threadIdx.x == 0)
    __hip_atomic_store(slots + (size_t)bid * 16, m, __ATOMIC_RELAXED,
                       __HIP_MEMORY_SCOPE_AGENT);
  unsigned* myslot = slots + (size_t)threadIdx.x * 16;
  for (int it = 0; it < (1 << 17); ++it) {
    if (__hip_atomic_load(myslot, __ATOMIC_RELAXED,
                          __HIP_MEMORY_SCOPE_AGENT) >= m)
      break;
    __builtin_amdgcn_s_sleep(2);
  }
  __syncthreads();
}

// =====================================================================
// Kernel B: persistent MFMA scan. 256 blocks x 256 thr (4 waves), 1/CU.
// Block (ng,kg): n-slice 64, k-slice 256. Split-bf16 (hh+hl+lh), fp32 acc.
//
// LDS is FRAGMENT-PACKED: slot[(tile*8+kc)*64+lane] holds the exact 16B
// bf16x8 fragment lane needs -> every ds_read/ds_write_b128 is
// lane-sequential (zero bank conflicts; R5 had 1.7e8 at 8-way).
//   A (h):  tile rt=0..3 covers rows rt*16+(lane&15), k kc*32+(lane>>4)*8
//   B (W):  tile nt=0..3 covers rows nt*16+(lane&15), same k pattern
//
// h[t-1] staged with NORMAL loads (L2-shared across the 32 blocks/XCD that
// read the same k-slice); safe because every step ends with
// fence(acquire,agent) (L2/L1 inv) and h was astore'd (write-through).
// Partials remain agent-scope (addresses reused every step).
// =====================================================================
__global__ __launch_bounds__(256) void ctrnn_scan(
    const float* __restrict__ Whh, float* out,
    float* __restrict__ partial, unsigned* slots)
{
  __shared__ __align__(16) uint4 HpA_hi[2048], HpA_lo[2048];  // 32KB each
  __shared__ __align__(16) uint4 HpB_hi[2048], HpB_lo[2048];  // total 128KB

  const int tid = threadIdx.x, bid = blockIdx.x;
  const int kg = bid & (KG - 1), ng = bid >> 3;
  const int n0 = ng * 64, k0 = kg * KR;

  const int lane = tid & 63, wid = tid >> 6;
  const int wb = wid & 1, wn = wid >> 1;     // wave tile: 32b x 32n

  // ---- stage W_hh slice ONCE into frag-packed B planes ----
  {
    const int s = tid >> 6, l = tid & 63;
    const int row = n0 + s * 16 + (l & 15);
    const int kq  = (l >> 4) * 8;
    const float* src = Whh + (size_t)row * H_DIM + k0 + kq;
    #pragma unroll
    for (int kc = 0; kc < 8; ++kc) {
      uint4 hi, lo;
      cvt8(src + kc * 32, hi, lo);
      const int slot = (s * 8 + kc) * 64 + l;
      HpB_hi[slot] = hi;
      HpB_lo[slot] = lo;
    }
  }

  // ---- register-resident h for my owned region o ----
  const size_t o = (size_t)bid * 512 + (size_t)tid * 2;
  float2 hreg = aload8(&out[o]);

  __builtin_amdgcn_fence(__ATOMIC_ACQUIRE, "agent");  // start clean

  for (int t = 1; t < T_DIM; ++t) {
    // ---------- phase A: stage h[t-1] (normal loads) -> frag-packed LDS ----
    const float* hprev = out + (size_t)(t - 1) * BH;
    {
      const int s = tid >> 6, l = tid & 63;
      const int row = s * 16 + (l & 15);
      const int kq  = (l >> 4) * 8;
      const float* src = hprev + (size_t)row * H_DIM + k0 + kq;
      #pragma unroll
      for (int kc = 0; kc < 8; ++kc) {
        uint4 hi, lo;
        cvt8(src + kc * 32, hi, lo);
        const int slot = (s * 8 + kc) * 64 + l;
        HpA_hi[slot] = hi;
        HpA_lo[slot] = lo;
      }
    }
    __syncthreads();

    // ---------- 64x64x256 MFMA (split-bf16: hh + hl + lh) ----------
    f32x4 acc[2][2];
    #pragma unroll
    for (int bt = 0; bt < 2; ++bt)
      #pragma unroll
      for (int nt = 0; nt < 2; ++nt)
        acc[bt][nt] = (f32x4){0.f, 0.f, 0.f, 0.f};

    #pragma unroll 2
    for (int kc = 0; kc < 8; ++kc) {
      bf16x8 ah[2], al[2], bh[2], bl[2];
      #pragma unroll
      for (int bt = 0; bt < 2; ++bt) {
        const int slot = ((wb * 2 + bt) * 8 + kc) * 64 + lane;
        ah[bt] = *(const bf16x8*)&HpA_hi[slot];
        al[bt] = *(const bf16x8*)&HpA_lo[slot];
      }
      #pragma unroll
      for (int nt = 0; nt < 2; ++nt) {
        const int slot = ((wn * 2 + nt) * 8 + kc) * 64 + lane;
        bh[nt] = *(const bf16x8*)&HpB_hi[slot];
        bl[nt] = *(const bf16x8*)&HpB_lo[slot];
      }
      #pragma unroll
      for (int bt = 0; bt < 2; ++bt)
        #pragma unroll
        for (int nt = 0; nt < 2; ++nt) {
          acc[bt][nt] = __builtin_amdgcn_mfma_f32_16x16x32_bf16(
              ah[bt], bh[nt], acc[bt][nt], 0, 0, 0);
          acc[bt][nt] = __builtin_amdgcn_mfma_f32_16x16x32_bf16(
              ah[bt], bl[nt], acc[bt][nt], 0, 0, 0);
          acc[bt][nt] = __builtin_amdgcn_mfma_f32_16x16x32_bf16(
              al[bt], bh[nt], acc[bt][nt], 0, 0, 0);
        }
    }

    // store partials (C layout: n = lane&15, b = (lane>>4)*4 + reg)
    {
      const int fr = lane & 15, fq = lane >> 4;
      float* pp = partial + (size_t)kg * BH;
      #pragma unroll
      for (int bt = 0; bt < 2; ++bt)
        #pragma unroll
        for (int nt = 0; nt < 2; ++nt) {
          const int n = n0 + wn * 32 + nt * 16 + fr;
          #pragma unroll
          for (int j = 0; j < 4; ++j) {
            const int b = wb * 32 + bt * 16 + fq * 4 + j;
            astore4(&pp[(size_t)b * H_DIM + n], acc[bt][nt][j]);
          }
        }
    }
    gbar(slots, 2 * t - 1, bid);

    // ---------- phase B: reduce + leaky-relu (register h) ----------
    {
      float sx = 0.f, sy = 0.f;
      #pragma unroll
      for (int q = 0; q < KG; ++q) {
        float2 p = aload8(&partial[(size_t)q * BH + o]);
        sx += p.x; sy += p.y;
      }
      float2 xin = *(const float2*)&out[(size_t)t * BH + o];  // region-private
      hreg.x = 0.99f * hreg.x + 0.01f * fmaxf(xin.x + sx, 0.f);
      hreg.y = 0.99f * hreg.y + 0.01f * fmaxf(xin.y + sy, 0.f);
      astore8(&out[(size_t)t * BH + o], hreg.x, hreg.y);
      if (t == T_DIM - 1)
        astore8(&out[(size_t)T_DIM * BH + o], hreg.x, hreg.y);  // h_last
    }
    gbar(slots, 2 * t, bid);
    // invalidate L1/L2 so next step's NORMAL h loads refetch coherent data
    __builtin_amdgcn_fence(__ATOMIC_ACQUIRE, "agent");
  }
}

// =====================================================================
extern "C" void kernel_launch(void* const* d_in, const int* in_sizes, int n_in,
                              void* d_out, int out_size, void* d_ws, size_t ws_size,
                              hipStream_t stream) {
  const float* x    = (const float*)d_in[0];
  const float* Wih  = (const float*)d_in[1];
  const float* bih  = (const float*)d_in[2];
  const float* Whh  = (const float*)d_in[3];
  const float* bhh  = (const float*)d_in[4];
  float* out = (float*)d_out;

  unsigned* slots = (unsigned*)d_ws;                    // 256 * 64B = 16 KB
  float* partial  = (float*)((char*)d_ws + 32768);      // KG*BH*4 = 4.2 MB

  hipMemsetAsync(d_ws, 0, 32768, stream);  // reset barrier slots every call

  xin_gemm<<<dim3(2048), dim3(256), 0, stream>>>(x, Wih, bih, bhh, out);
  ctrnn_scan<<<dim3(NBLK), dim3(256), 0, stream>>>(Whh, out, partial, slots);
}

// Round 7
// 3777.539 us; speedup vs baseline: 1.1967x; 1.1967x over previous
//
#include <hip/hip_runtime.h>

// Problem dims (fixed by setup_inputs): T=256, B=64, I=512, H=2048
#define T_DIM 256
#define B_DIM 64
#define I_DIM 512
#define H_DIM 2048
#define BH (B_DIM * H_DIM)      // 131072 floats per timestep slice
#define NBLK 256                // persistent grid: 1 block per CU
#define PUB_U64 32768           // one parity: 16384 slots * 2 u64 (256 KB)

typedef __attribute__((ext_vector_type(8))) short bf16x8;
typedef __attribute__((ext_vector_type(4))) float f32x4;

// ---------------------------------------------------------------------
// Agent-scope ops (validated R4-R6): write-through stores visible at the
// device coherence point; normal loads + per-step acquire fence (L2 inv)
// give cross-XCD read sharing with L2 dedup.
// ---------------------------------------------------------------------
__device__ __forceinline__ void astore4(float* p, float a) {
  union { unsigned u; float f; } c; c.f = a;
  __hip_atomic_store((unsigned*)p, c.u, __ATOMIC_RELAXED,
                     __HIP_MEMORY_SCOPE_AGENT);
}
__device__ __forceinline__ void astoreU(unsigned long long* p,
                                        unsigned long long v) {
  __hip_atomic_store(p, v, __ATOMIC_RELAXED, __HIP_MEMORY_SCOPE_AGENT);
}

// bf16 split helpers
__device__ __forceinline__ unsigned bf16_rne(float x) {
  union { float f; unsigned u; } c; c.f = x;
  return (c.u + 0x7FFFu + ((c.u >> 16) & 1u)) >> 16;
}
__device__ __forceinline__ float bf16_to_f(unsigned b) {
  union { float f; unsigned u; } c; c.u = b << 16; return c.f;
}
__device__ __forceinline__ void cvt_pair(float x0, float x1,
                                         unsigned& hi, unsigned& lo) {
  unsigned h0 = bf16_rne(x0), h1 = bf16_rne(x1);
  float r0 = x0 - bf16_to_f(h0), r1 = x1 - bf16_to_f(h1);
  unsigned l0 = bf16_rne(r0), l1 = bf16_rne(r1);
  hi = h0 | (h1 << 16);
  lo = l0 | (l1 << 16);
}
__device__ __forceinline__ void cvt8(const float* s, uint4& hi, uint4& lo) {
  float4 a = *(const float4*)s;
  float4 b = *(const float4*)(s + 4);
  cvt_pair(a.x, a.y, hi.x, lo.x);
  cvt_pair(a.z, a.w, hi.y, lo.y);
  cvt_pair(b.x, b.y, hi.z, lo.z);
  cvt_pair(b.z, b.w, hi.w, lo.w);
}

// =====================================================================
// Kernel A: xin = x @ W_ih^T + b_ih + b_hh  (rows m<64 fold t=0:
// out[0] = 0.01*relu(xin[0])).  Unchanged (fp32 VALU, ~230us).
// =====================================================================
__global__ __launch_bounds__(256) void xin_gemm(
    const float* __restrict__ x, const float* __restrict__ Wih,
    const float* __restrict__ bih, const float* __restrict__ bhh,
    float* __restrict__ out)
{
  __shared__ __align__(16) float As[16][132];
  __shared__ __align__(16) float Bs[16][132];
  const int tid = threadIdx.x;
  const int nb = blockIdx.x & 15, mb = blockIdx.x >> 4;
  const int m0 = mb * 128, n0 = nb * 128;
  const int tx = tid & 15, ty = tid >> 4;

  float acc[8][8];
  #pragma unroll
  for (int i = 0; i < 8; ++i)
    #pragma unroll
    for (int j = 0; j < 8; ++j) acc[i][j] = 0.f;

  for (int k0 = 0; k0 < I_DIM; k0 += 16) {
    __syncthreads();
    {
      const int r = tid >> 1;
      #pragma unroll
      for (int c = 0; c < 2; ++c) {
        const int kq = (tid & 1) * 4 + c * 8;
        float4 va = *(const float4*)&x[(size_t)(m0 + r) * I_DIM + k0 + kq];
        As[kq + 0][r] = va.x; As[kq + 1][r] = va.y;
        As[kq + 2][r] = va.z; As[kq + 3][r] = va.w;
        float4 vb = *(const float4*)&Wih[(size_t)(n0 + r) * I_DIM + k0 + kq];
        Bs[kq + 0][r] = vb.x; Bs[kq + 1][r] = vb.y;
        Bs[kq + 2][r] = vb.z; Bs[kq + 3][r] = vb.w;
      }
    }
    __syncthreads();
    #pragma unroll 4
    for (int k = 0; k < 16; ++k) {
      float a[8], b[8];
      *(float4*)&a[0] = *(const float4*)&As[k][ty * 8];
      *(float4*)&a[4] = *(const float4*)&As[k][ty * 8 + 4];
      *(float4*)&b[0] = *(const float4*)&Bs[k][tx * 4];
      *(float4*)&b[4] = *(const float4*)&Bs[k][64 + tx * 4];
      #pragma unroll
      for (int i = 0; i < 8; ++i)
        #pragma unroll
        for (int j = 0; j < 8; ++j) acc[i][j] += a[i] * b[j];
    }
  }

  float bb[8];
  #pragma unroll
  for (int j = 0; j < 4; ++j) {
    bb[j]     = bih[n0 + tx * 4 + j]      + bhh[n0 + tx * 4 + j];
    bb[4 + j] = bih[n0 + 64 + tx * 4 + j] + bhh[n0 + 64 + tx * 4 + j];
  }
  #pragma unroll
  for (int i = 0; i < 8; ++i) {
    const int m = m0 + ty * 8 + i;
    float v[8];
    #pragma unroll
    for (int j = 0; j < 8; ++j) v[j] = acc[i][j] + bb[j];
    if (m < B_DIM) {
      #pragma unroll
      for (int j = 0; j < 8; ++j) v[j] = 0.01f * fmaxf(v[j], 0.f);
    }
    *(float4*)&out[(size_t)m * H_DIM + n0 + tx * 4] =
        make_float4(v[0], v[1], v[2], v[3]);
    *(float4*)&out[(size_t)m * H_DIM + n0 + 64 + tx * 4] =
        make_float4(v[4], v[5], v[6], v[7]);
  }
}

// ---------------------------------------------------------------------
// Fence-free grid barrier (validated R4-R6).
// ---------------------------------------------------------------------
__device__ __forceinline__ void gbar(unsigned* slots, unsigned m, int bid) {
  asm volatile("s_waitcnt vmcnt(0) lgkmcnt(0)" ::: "memory");
  __syncthreads();
  if (threadIdx.x == 0)
    __hip_atomic_store(slots + (size_t)bid * 16, m, __ATOMIC_RELAXED,
                       __HIP_MEMORY_SCOPE_AGENT);
  unsigned* myslot = slots + (size_t)threadIdx.x * 16;
  for (int it = 0; it < (1 << 17); ++it) {
    if (__hip_atomic_load(myslot, __ATOMIC_RELAXED,
                          __HIP_MEMORY_SCOPE_AGENT) >= m)
      break;
    __builtin_amdgcn_s_sleep(2);
  }
  __syncthreads();
}

// =====================================================================
// Kernel B: ONE-barrier-per-step persistent scan.
// 256 blocks x 256 thr (4 waves). Block (bh,nb) owns region
// b in [bh*32, +32), n in [nb*16, +16), FULL K=2048 (no k-split, no
// partial round-trip). W slice (16n x 2048k, split-bf16 hi+lo) in LDS
// forever (128 KB). h operand lives in a double-buffered global "pub"
// buffer as bf16 MFMA-A fragments (slot[k8*64+b] = 8 bf16 of row b,
// k8*8..+8) -> consumers load A-frags DIRECTLY global->VGPR (L2-dedup'd
// across the XCD; no LDS staging, no consumer cvt).
// Waves split K (4 x 512), cross-wave reduce in LDS (8 KB), owner
// updates fp32-register h, astores out[t], publishes bf16 h[t] to the
// other parity. One gbar per step; per-step acquire fence invalidates
// L2 so pub/out reads refetch coherently (pattern validated R6).
// =====================================================================
__global__ __launch_bounds__(256) void ctrnn_scan(
    const float* __restrict__ Whh, float* out,
    unsigned long long* __restrict__ pub, unsigned* slots)
{
  __shared__ __align__(16) uint4 Whi[4096];   // 64 KB
  __shared__ __align__(16) uint4 Wlo[4096];   // 64 KB
  __shared__ __align__(16) f32x4 Red[512];    // 8 KB
  __shared__ unsigned short Hs[32][16];       // 1 KB bf16 publish staging

  const int tid = threadIdx.x, bid = blockIdx.x;
  const int nb = bid & 127, bh = bid >> 7;
  const int n0 = nb * 16, b0 = bh * 32;

  const int lane = tid & 63, wid = tid >> 6;
  const int fr = lane & 15, fq = lane >> 4;

  // ---- stage W slice ONCE: rows n0..n0+16, all k, frag-packed hi/lo ----
  for (int s = tid; s < 4096; s += 256) {
    const int kcg = s >> 6, l = s & 63;
    const int n = n0 + (l & 15), k = kcg * 32 + (l >> 4) * 8;
    uint4 hi, lo;
    cvt8(&Whh[(size_t)n * H_DIM + k], hi, lo);
    Whi[s] = hi; Wlo[s] = lo;
  }

  // ---- ownership mapping (matches MFMA C layout: col=lane&15=n,
  //      row=(lane>>4)*4+j=b). Thread owns j=jh*2 and jh*2+1. ----
  const int bt = tid >> 7, jh = (tid >> 6) & 1, ln = tid & 63;
  const int rfr = ln & 15, rfq = ln >> 4;
  const int bl0 = bt * 16 + rfq * 4 + jh * 2;            // local b of 1st
  const size_t oa0 = (size_t)(b0 + bl0) * H_DIM + n0 + rfr;
  const size_t oa1 = oa0 + H_DIM;

  // fp32 h state in registers (h[0] = out[0], t=0 folded in xin_gemm)
  float h0 = out[oa0];
  float h1 = out[oa1];

  // ---- publish h[0] as bf16 frags to pub parity 0 ----
  Hs[bl0][rfr]     = (unsigned short)bf16_rne(h0);
  Hs[bl0 + 1][rfr] = (unsigned short)bf16_rne(h1);
  __syncthreads();   // also covers W staging completion
  if (tid < 64) {
    const int b_l = tid & 31, h8 = tid >> 5;
    const uint4 frag = *(const uint4*)&Hs[b_l][h8 * 8];
    const size_t slot = (size_t)(nb * 2 + h8) * 64 + b0 + b_l;
    astoreU(&pub[slot * 2 + 0], ((const unsigned long long*)&frag)[0]);
    astoreU(&pub[slot * 2 + 1], ((const unsigned long long*)&frag)[1]);
  }

  const int baseA = wid * 4096 + fq * 64 + b0 + fr;  // slot idx, +kc*256
  const int baseB = wid * 1024;                      // +kc*64+lane

  for (int t = 1; t < T_DIM; ++t) {
    gbar(slots, t, bid);   // vmcnt(0) inside drains publishes first
    __builtin_amdgcn_fence(__ATOMIC_ACQUIRE, "agent");  // L1/L2 inv

    // prefetch xin for own region (MALL latency hides under GEMM)
    const float xin0 = out[(size_t)t * BH + oa0];
    const float xin1 = out[(size_t)t * BH + oa1];

    const uint4* pr = (const uint4*)(pub + (size_t)((t - 1) & 1) * PUB_U64);

    // ---- GEMM: this wave covers k in [wid*512, +512) ----
    f32x4 acc0 = {0.f, 0.f, 0.f, 0.f}, acc1 = {0.f, 0.f, 0.f, 0.f};
    #pragma unroll
    for (int kc = 0; kc < 16; ++kc) {
      const uint4 a0 = pr[baseA + kc * 256];        // A-frag, btile 0
      const uint4 a1 = pr[baseA + kc * 256 + 16];   // A-frag, btile 1
      const uint4 bh4 = Whi[baseB + kc * 64 + lane];
      const uint4 bl4 = Wlo[baseB + kc * 64 + lane];
      acc0 = __builtin_amdgcn_mfma_f32_16x16x32_bf16(
          *(const bf16x8*)&a0, *(const bf16x8*)&bh4, acc0, 0, 0, 0);
      acc0 = __builtin_amdgcn_mfma_f32_16x16x32_bf16(
          *(const bf16x8*)&a0, *(const bf16x8*)&bl4, acc0, 0, 0, 0);
      acc1 = __builtin_amdgcn_mfma_f32_16x16x32_bf16(
          *(const bf16x8*)&a1, *(const bf16x8*)&bh4, acc1, 0, 0, 0);
      acc1 = __builtin_amdgcn_mfma_f32_16x16x32_bf16(
          *(const bf16x8*)&a1, *(const bf16x8*)&bl4, acc1, 0, 0, 0);
    }

    // ---- cross-wave K reduce ----
    Red[(wid * 2 + 0) * 64 + lane] = acc0;
    Red[(wid * 2 + 1) * 64 + lane] = acc1;
    __syncthreads();

    float s0 = 0.f, s1 = 0.f;
    #pragma unroll
    for (int w = 0; w < 4; ++w) {
      const float2 p = *(const float2*)(
          (const char*)&Red[(w * 2 + bt) * 64 + ln] + jh * 8);
      s0 += p.x; s1 += p.y;
    }

    // ---- leaky-relu update (fp32 register state) + output ----
    h0 = 0.99f * h0 + 0.01f * fmaxf(xin0 + s0, 0.f);
    h1 = 0.99f * h1 + 0.01f * fmaxf(xin1 + s1, 0.f);
    astore4(&out[(size_t)t * BH + oa0], h0);
    astore4(&out[(size_t)t * BH + oa1], h1);
    if (t == T_DIM - 1) {
      astore4(&out[(size_t)T_DIM * BH + oa0], h0);  // h_last
      astore4(&out[(size_t)T_DIM * BH + oa1], h1);
    }

    // ---- publish bf16 h[t] to parity t&1 ----
    __syncthreads();   // Red reads done; safe to reuse Hs
    Hs[bl0][rfr]     = (unsigned short)bf16_rne(h0);
    Hs[bl0 + 1][rfr] = (unsigned short)bf16_rne(h1);
    __syncthreads();
    if (tid < 64) {
      const int b_l = tid & 31, h8 = tid >> 5;
      const uint4 frag = *(const uint4*)&Hs[b_l][h8 * 8];
      const size_t slot = (size_t)(nb * 2 + h8) * 64 + b0 + b_l;
      unsigned long long* pw =
          pub + (size_t)(t & 1) * PUB_U64 + slot * 2;
      astoreU(pw + 0, ((const unsigned long long*)&frag)[0]);
      astoreU(pw + 1, ((const unsigned long long*)&frag)[1]);
    }
    // next gbar's vmcnt(0) drains these publishes before signaling
  }
}

// =====================================================================
extern "C" void kernel_launch(void* const* d_in, const int* in_sizes, int n_in,
                              void* d_out, int out_size, void* d_ws, size_t ws_size,
                              hipStream_t stream) {
  const float* x    = (const float*)d_in[0];
  const float* Wih  = (const float*)d_in[1];
  const float* bih  = (const float*)d_in[2];
  const float* Whh  = (const float*)d_in[3];
  const float* bhh  = (const float*)d_in[4];
  float* out = (float*)d_out;

  unsigned* slots = (unsigned*)d_ws;                          // 16 KB used
  unsigned long long* pub =
      (unsigned long long*)((char*)d_ws + 32768);             // 512 KB

  hipMemsetAsync(d_ws, 0, 32768, stream);  // reset barrier slots every call

  xin_gemm<<<dim3(2048), dim3(256), 0, stream>>>(x, Wih, bih, bhh, out);
  ctrnn_scan<<<dim3(NBLK), dim3(256), 0, stream>>>(Whh, out, pub, slots);
}